// Round 2
// baseline (1032.247 us; speedup 1.0000x reference)
//
#include <hip/hip_runtime.h>
#include <cstdint>

// ---------------- problem constants ----------------
static constexpr long long Bb = 16, Nn = 1024, FE = 512; // heads=2, g=512
static constexpr long long BN = Bb * Nn;        // 16384
static constexpr long long E1 = BN * FE;        // 8,388,608  elems of [B,N,FE]
static constexpr long long E2n = BN * Nn;       // 16,777,216 elems of [B,N,N]

// ---------------- workspace layout (bytes) ----------------
static constexpr long long O_WT  = 0;
static constexpr long long SZ_W512 = FE * FE * 2;          // 512x512 bf16
static constexpr long long O_WQT = O_WT + 6 * SZ_W512;
static constexpr long long SZ_W1K = Nn * Nn * 2;           // 1024x1024 bf16
static constexpr long long O_WKT = O_WQT + SZ_W1K;
static constexpr long long O_WVT = O_WKT + SZ_W1K;
static constexpr long long O_F1T = O_WVT + SZ_W1K;
static constexpr long long O_F2T = O_F1T + SZ_W1K;
static constexpr long long O_SLOTS = O_F2T + SZ_W1K;       // 13,631,488
static constexpr long long SLOT = E2n * 2;                 // 32 MiB
static constexpr long long O_S0 = O_SLOTS;                 // Fs/Fq bf16 -> Q -> o
static constexpr long long O_S1 = O_S0 + SLOT;             // P pair -> K -> x
static constexpr long long O_S2 = O_S1 + SLOT;             // Fms bf16 -> Vt -> h
static constexpr long long O_E0 = O_S2 + SLOT;             // ass -> attn0
static constexpr long long O_E1 = O_E0 + SLOT;             // asq -> attn1
static constexpr long long O_E2 = O_E1 + SLOT;             // aqq (persists to LN1)
static constexpr long long WS_NEED = O_E2 + SLOT;          // 214,958,080 (~205 MiB)

// ---------------- helpers ----------------
typedef __attribute__((ext_vector_type(8))) short short8;
typedef __attribute__((ext_vector_type(4))) float f32x4;

static __device__ __forceinline__ unsigned short f2bf(float f) {
  union { float f; unsigned u; } x; x.f = f;
  unsigned r = x.u + 0x7FFFu + ((x.u >> 16) & 1u);
  return (unsigned short)(r >> 16);
}
static __device__ __forceinline__ float bf2f(unsigned short h) {
  union { unsigned u; float f; } x; x.u = ((unsigned)h) << 16; return x.f;
}
static __device__ __forceinline__ void gload16(const void* g, void* l) {
  __builtin_amdgcn_global_load_lds(
      (const __attribute__((address_space(1))) unsigned int*)g,
      (__attribute__((address_space(3))) unsigned int*)l, 16, 0, 0);
}

// ---------------- bf16 NT GEMM: C[m,n] = sum_k A[m,k]*B[n,k] ----------------
// m97 structure: 128x128 tile, BK=32, 16x16x32 MFMA, global_load_lds width 16.
// EP: 0 = f32 out, 1 = bf16 out, 2 = bf16 relu out, 3 = f32 out + bf16 residual R.
template <int EP>
__global__ __launch_bounds__(256) void gemm_nt(
    const unsigned short* __restrict__ A, long long sA, int lda,
    const unsigned short* __restrict__ B, long long sB, int ldb,
    void* __restrict__ Cv, long long sC, int ldc,
    const void* __restrict__ Rv, long long sR, int K) {
  __shared__ unsigned short lA[128 * 32];
  __shared__ unsigned short lB[128 * 32];
  const int tid = threadIdx.x;
  const int wave = tid >> 6, lane = tid & 63;
  const int wm = wave >> 1, wn = wave & 1;
  const int lrow = lane & 15, quad = lane >> 4;
  const int z = blockIdx.z;
  const long long bm = (long long)blockIdx.x * 128;
  const long long bn = (long long)blockIdx.y * 128;
  const unsigned short* Ab = A + (long long)z * sA + bm * lda;
  const unsigned short* Bbp = B + (long long)z * sB + bn * ldb;
  const int srow = lane >> 2;        // row within 16-row group
  const int skol = (lane & 3) * 8;   // 8-elem k-offset
  const int g0 = wave * 2, g1 = wave * 2 + 1;

  f32x4 acc[4][4];
#pragma unroll
  for (int i = 0; i < 4; ++i)
#pragma unroll
    for (int j = 0; j < 4; ++j) acc[i][j] = (f32x4){0.f, 0.f, 0.f, 0.f};

  for (int k0 = 0; k0 < K; k0 += 32) {
    gload16(Ab + (long long)(g0 * 16 + srow) * lda + k0 + skol, &lA[g0 * 512 + lane * 8]);
    gload16(Ab + (long long)(g1 * 16 + srow) * lda + k0 + skol, &lA[g1 * 512 + lane * 8]);
    gload16(Bbp + (long long)(g0 * 16 + srow) * ldb + k0 + skol, &lB[g0 * 512 + lane * 8]);
    gload16(Bbp + (long long)(g1 * 16 + srow) * ldb + k0 + skol, &lB[g1 * 512 + lane * 8]);
    __syncthreads();
    short8 af[4], bfr[4];
#pragma unroll
    for (int t = 0; t < 4; ++t) {
      af[t]  = *(const short8*)&lA[(wm * 64 + t * 16 + lrow) * 32 + quad * 8];
      bfr[t] = *(const short8*)&lB[(wn * 64 + t * 16 + lrow) * 32 + quad * 8];
    }
#pragma unroll
    for (int mt = 0; mt < 4; ++mt)
#pragma unroll
      for (int nt = 0; nt < 4; ++nt)
        acc[mt][nt] = __builtin_amdgcn_mfma_f32_16x16x32_bf16(af[mt], bfr[nt], acc[mt][nt], 0, 0, 0);
    __syncthreads();
  }
  // epilogue: C/D map col=lane&15, row=quad*4+r (verified m89/m91)
  const long long cm = bm + wm * 64, cn = bn + wn * 64;
#pragma unroll
  for (int mt = 0; mt < 4; ++mt) {
#pragma unroll
    for (int nt = 0; nt < 4; ++nt) {
      long long col = cn + nt * 16 + lrow;
      long long row0 = cm + mt * 16 + quad * 4;
#pragma unroll
      for (int r = 0; r < 4; ++r) {
        long long row = row0 + r;
        float v = acc[mt][nt][r];
        long long idx = (long long)z * sC + row * ldc + col;
        if (EP == 0) ((float*)Cv)[idx] = v;
        else if (EP == 1) ((unsigned short*)Cv)[idx] = f2bf(v);
        else if (EP == 2) ((unsigned short*)Cv)[idx] = f2bf(v > 0.f ? v : 0.f);
        else {
          float rr = bf2f(((const unsigned short*)Rv)[(long long)z * sR + row * ldc + col]);
          ((float*)Cv)[idx] = v + rr;
        }
      }
    }
  }
}

// ---------------- elementwise cast f32 -> bf16 ----------------
__global__ __launch_bounds__(256) void cast_bf16_k(const float* __restrict__ in,
                                                   unsigned short* __restrict__ out) {
  long long i = (long long)blockIdx.x * 256 + threadIdx.x;
  float4 v = ((const float4*)in)[i];
  ushort4 o; o.x = f2bf(v.x); o.y = f2bf(v.y); o.z = f2bf(v.z); o.w = f2bf(v.w);
  ((ushort4*)out)[i] = o;
}

// ---------------- transpose + cast f32 -> bf16: out[c][r] = in[r][c] ----------------
__global__ __launch_bounds__(256) void tcast_k(const float* __restrict__ in,
                                               unsigned short* __restrict__ out,
                                               int rows, int cols) {
  __shared__ float t[32][33];
  const int c0 = blockIdx.x * 32, r0 = blockIdx.y * 32;
  const int tx = threadIdx.x, ty = threadIdx.y; // block (32,8)
#pragma unroll
  for (int i = 0; i < 4; ++i) {
    int r = r0 + ty + i * 8;
    t[ty + i * 8][tx] = in[(long long)r * cols + c0 + tx];
  }
  __syncthreads();
#pragma unroll
  for (int i = 0; i < 4; ++i) {
    int c = c0 + ty + i * 8;
    out[(long long)c * rows + r0 + tx] = f2bf(t[tx][ty + i * 8]);
  }
}

// ---------------- in-place row softmax over bf16 (1024 cols), scaled ----------------
__global__ __launch_bounds__(256) void softmax_bf(unsigned short* __restrict__ S, float scale) {
  __shared__ float redA[4], redB[4];
  const long long row = blockIdx.x;
  const int t = threadIdx.x, wave = t >> 6, lane = t & 63;
  ushort4 u = ((ushort4*)(S + row * 1024))[t];
  float v0 = bf2f(u.x) * scale, v1 = bf2f(u.y) * scale, v2 = bf2f(u.z) * scale, v3 = bf2f(u.w) * scale;
  float m = fmaxf(fmaxf(v0, v1), fmaxf(v2, v3));
#pragma unroll
  for (int o = 32; o; o >>= 1) m = fmaxf(m, __shfl_down(m, o));
  if (lane == 0) redA[wave] = m;
  __syncthreads();
  m = fmaxf(fmaxf(redA[0], redA[1]), fmaxf(redA[2], redA[3]));
  float e0 = __expf(v0 - m), e1 = __expf(v1 - m), e2 = __expf(v2 - m), e3 = __expf(v3 - m);
  float s = e0 + e1 + e2 + e3;
#pragma unroll
  for (int o = 32; o; o >>= 1) s += __shfl_down(s, o);
  if (lane == 0) redB[wave] = s;
  __syncthreads();
  s = redB[0] + redB[1] + redB[2] + redB[3];
  float inv = 1.f / s;
  ushort4 ob; ob.x = f2bf(e0 * inv); ob.y = f2bf(e1 * inv); ob.z = f2bf(e2 * inv); ob.w = f2bf(e3 * inv);
  ((ushort4*)(S + row * 1024))[t] = ob;
}

// ---------------- LN1: x = LN(o + aqq)*g + b -> bf16 ----------------
__global__ __launch_bounds__(256) void ln1_k(const unsigned short* __restrict__ O,
                                             const unsigned short* __restrict__ Aq,
                                             const float* __restrict__ g, const float* __restrict__ b,
                                             unsigned short* __restrict__ xb) {
  __shared__ float redA[4], redB[4];
  const long long row = blockIdx.x;
  const int t = threadIdx.x, wave = t >> 6, lane = t & 63;
  ushort4 ou = ((const ushort4*)(O + row * 1024))[t];
  ushort4 au = ((const ushort4*)(Aq + row * 1024))[t];
  float v0 = bf2f(ou.x) + bf2f(au.x), v1 = bf2f(ou.y) + bf2f(au.y);
  float v2 = bf2f(ou.z) + bf2f(au.z), v3 = bf2f(ou.w) + bf2f(au.w);
  float s = v0 + v1 + v2 + v3;
  float q = v0 * v0 + v1 * v1 + v2 * v2 + v3 * v3;
#pragma unroll
  for (int o = 32; o; o >>= 1) { s += __shfl_down(s, o); q += __shfl_down(q, o); }
  if (lane == 0) { redA[wave] = s; redB[wave] = q; }
  __syncthreads();
  float S = redA[0] + redA[1] + redA[2] + redA[3];
  float Q = redB[0] + redB[1] + redB[2] + redB[3];
  float mu = S * (1.f / 1024.f);
  float var = Q * (1.f / 1024.f) - mu * mu;
  float rs = rsqrtf(var + 1e-5f);
  float4 gg = ((const float4*)g)[t], bbv = ((const float4*)b)[t];
  ushort4 ob;
  ob.x = f2bf((v0 - mu) * rs * gg.x + bbv.x);
  ob.y = f2bf((v1 - mu) * rs * gg.y + bbv.y);
  ob.z = f2bf((v2 - mu) * rs * gg.z + bbv.z);
  ob.w = f2bf((v3 - mu) * rs * gg.w + bbv.w);
  ((ushort4*)(xb + row * 1024))[t] = ob;
}

// ---------------- LN2: y = LN(y0)*g + b, f32 in-place safe ----------------
__global__ __launch_bounds__(256) void ln2_k(const float* __restrict__ Y,
                                             const float* __restrict__ g, const float* __restrict__ b,
                                             float* __restrict__ out, float eps) {
  __shared__ float redA[4], redB[4];
  const long long row = blockIdx.x;
  const int t = threadIdx.x, wave = t >> 6, lane = t & 63;
  float4 v = ((const float4*)(Y + row * 1024))[t];
  float s = v.x + v.y + v.z + v.w;
  float q = v.x * v.x + v.y * v.y + v.z * v.z + v.w * v.w;
#pragma unroll
  for (int o = 32; o; o >>= 1) { s += __shfl_down(s, o); q += __shfl_down(q, o); }
  if (lane == 0) { redA[wave] = s; redB[wave] = q; }
  __syncthreads();
  float S = redA[0] + redA[1] + redA[2] + redA[3];
  float Q = redB[0] + redB[1] + redB[2] + redB[3];
  float mu = S * (1.f / 1024.f);
  float var = Q * (1.f / 1024.f) - mu * mu;
  float rs = rsqrtf(var + eps);
  float4 gg = ((const float4*)g)[t], bbv = ((const float4*)b)[t];
  float4 o;
  o.x = (v.x - mu) * rs * gg.x + bbv.x;
  o.y = (v.y - mu) * rs * gg.y + bbv.y;
  o.z = (v.z - mu) * rs * gg.z + bbv.z;
  o.w = (v.w - mu) * rs * gg.w + bbv.w;
  ((float4*)(out + row * 1024))[t] = o;
}

// ---------------- launcher ----------------
extern "C" void kernel_launch(void* const* d_in, const int* in_sizes, int n_in,
                              void* d_out, int out_size, void* d_ws, size_t ws_size,
                              hipStream_t stream) {
  (void)in_sizes; (void)n_in; (void)out_size;
  // Diagnostic guard: if ws too small, do nothing -> output stays 0, absmax ~= 7.09
  if (ws_size < (size_t)WS_NEED) return;

  const float* Fs  = (const float*)d_in[0];
  const float* Fq  = (const float*)d_in[1];
  const float* Fms = (const float*)d_in[2];
  const float* Wm[6] = {(const float*)d_in[4], (const float*)d_in[5], (const float*)d_in[6],
                        (const float*)d_in[7], (const float*)d_in[8], (const float*)d_in[9]};
  const float* Wq = (const float*)d_in[10];
  const float* Wk = (const float*)d_in[11];
  const float* Wv = (const float*)d_in[12];
  const float* ln_g = (const float*)d_in[13];
  const float* ln_b = (const float*)d_in[14];
  const float* fw1 = (const float*)d_in[15];
  const float* fw2 = (const float*)d_in[16];
  const float* fg = (const float*)d_in[17];
  const float* fb = (const float*)d_in[18];
  float* out = (float*)d_out;
  uint8_t* ws = (uint8_t*)d_ws;
  auto U16 = [&](long long off) { return (unsigned short*)(ws + off); };

  const float inv_sqrt512 = 0.04419417382415922f; // 1/sqrt(512); also 1/sqrt(g), g=512
  dim3 blk(256);

  auto gemm = [&](int ep, const unsigned short* A, long long sA, int lda,
                  const unsigned short* B, long long sB, int ldb,
                  void* C, long long sC, int ldc, const void* R, long long sR,
                  int M, int N, int K, int batch) {
    dim3 g(M / 128, N / 128, batch);
    switch (ep) {
      case 0: gemm_nt<0><<<g, blk, 0, stream>>>(A, sA, lda, B, sB, ldb, C, sC, ldc, R, sR, K); break;
      case 1: gemm_nt<1><<<g, blk, 0, stream>>>(A, sA, lda, B, sB, ldb, C, sC, ldc, R, sR, K); break;
      case 2: gemm_nt<2><<<g, blk, 0, stream>>>(A, sA, lda, B, sB, ldb, C, sC, ldc, R, sR, K); break;
      default: gemm_nt<3><<<g, blk, 0, stream>>>(A, sA, lda, B, sB, ldb, C, sC, ldc, R, sR, K); break;
    }
  };

  // ---- weights: transpose+cast to bf16 ----
  for (int i = 0; i < 6; ++i)
    tcast_k<<<dim3(16, 16), dim3(32, 8), 0, stream>>>(Wm[i], U16(O_WT + (long long)i * SZ_W512), 512, 512);
  tcast_k<<<dim3(32, 32), dim3(32, 8), 0, stream>>>(Wq,  U16(O_WQT), 1024, 1024);
  tcast_k<<<dim3(32, 32), dim3(32, 8), 0, stream>>>(Wk,  U16(O_WKT), 1024, 1024);
  tcast_k<<<dim3(32, 32), dim3(32, 8), 0, stream>>>(Wv,  U16(O_WVT), 1024, 1024);
  tcast_k<<<dim3(32, 32), dim3(32, 8), 0, stream>>>(fw1, U16(O_F1T), 1024, 1024);
  tcast_k<<<dim3(32, 32), dim3(32, 8), 0, stream>>>(fw2, U16(O_F2T), 1024, 1024);

  unsigned short* FmsB = U16(O_S2);
  unsigned short* FsB  = U16(O_S0);
  unsigned short* FqB  = U16(O_S0 + E1 * 2);
  unsigned short* Pa   = U16(O_S1);
  unsigned short* Pb   = U16(O_S1 + E1 * 2);

  // ---- Phase A: affinities ----
  // ass = softmax(Fms W1 (Fms W2)^T / sqrt(512)) -> E0
  cast_bf16_k<<<dim3(E1 / 4 / 256), blk, 0, stream>>>(Fms, FmsB);
  gemm(1, FmsB, 0, 512, U16(O_WT + 0 * SZ_W512), 0, 512, Pa, 0, 512, nullptr, 0, (int)BN, 512, 512, 1);
  gemm(1, FmsB, 0, 512, U16(O_WT + 1 * SZ_W512), 0, 512, Pb, 0, 512, nullptr, 0, (int)BN, 512, 512, 1);
  gemm(1, Pa, Nn * FE, 512, Pb, Nn * FE, 512, U16(O_E0), Nn * Nn, 1024, nullptr, 0, 1024, 1024, 512, (int)Bb);
  softmax_bf<<<dim3(BN), blk, 0, stream>>>(U16(O_E0), inv_sqrt512);
  // asq -> E1
  cast_bf16_k<<<dim3(E1 / 4 / 256), blk, 0, stream>>>(Fs, FsB);
  cast_bf16_k<<<dim3(E1 / 4 / 256), blk, 0, stream>>>(Fq, FqB);
  gemm(1, FsB, 0, 512, U16(O_WT + 2 * SZ_W512), 0, 512, Pa, 0, 512, nullptr, 0, (int)BN, 512, 512, 1);
  gemm(1, FqB, 0, 512, U16(O_WT + 3 * SZ_W512), 0, 512, Pb, 0, 512, nullptr, 0, (int)BN, 512, 512, 1);
  gemm(1, Pa, Nn * FE, 512, Pb, Nn * FE, 512, U16(O_E1), Nn * Nn, 1024, nullptr, 0, 1024, 1024, 512, (int)Bb);
  softmax_bf<<<dim3(BN), blk, 0, stream>>>(U16(O_E1), inv_sqrt512);
  // aqq -> E2
  gemm(1, FqB, 0, 512, U16(O_WT + 4 * SZ_W512), 0, 512, Pa, 0, 512, nullptr, 0, (int)BN, 512, 512, 1);
  gemm(1, FqB, 0, 512, U16(O_WT + 5 * SZ_W512), 0, 512, Pb, 0, 512, nullptr, 0, (int)BN, 512, 512, 1);
  gemm(1, Pa, Nn * FE, 512, Pb, Nn * FE, 512, U16(O_E2), Nn * Nn, 1024, nullptr, 0, 1024, 1024, 512, (int)Bb);
  softmax_bf<<<dim3(BN), blk, 0, stream>>>(U16(O_E2), inv_sqrt512);

  const unsigned short* assB = U16(O_E0);
  const unsigned short* asqB = U16(O_E1);

  // ---- Phase B ----
  // Q = asq@Wq -> S0 ; K = ass@Wk -> S1 ; Vt[b][c][q] = V[b][q][c] -> S2 (swapped NT)
  gemm(1, asqB, 0, 1024, U16(O_WQT), 0, 1024, U16(O_S0), 0, 1024, nullptr, 0, (int)BN, 1024, 1024, 1);
  gemm(1, assB, 0, 1024, U16(O_WKT), 0, 1024, U16(O_S1), 0, 1024, nullptr, 0, (int)BN, 1024, 1024, 1);
  gemm(1, U16(O_WVT), 0, 1024, asqB, Nn * Nn, 1024, U16(O_S2), Nn * Nn, 1024, nullptr, 0, 1024, 1024, 1024, (int)Bb);

  // attention per head: scores (bf16) into E0/E1 (ass/asq now dead), softmax in place
  gemm(1, U16(O_S0) + 0,   Nn * Nn, 1024, U16(O_S1) + 0,   Nn * Nn, 1024, U16(O_E0), Nn * Nn, 1024, nullptr, 0, 1024, 1024, 512, (int)Bb);
  softmax_bf<<<dim3(BN), blk, 0, stream>>>(U16(O_E0), inv_sqrt512);
  gemm(1, U16(O_S0) + 512, Nn * Nn, 1024, U16(O_S1) + 512, Nn * Nn, 1024, U16(O_E1), Nn * Nn, 1024, nullptr, 0, 1024, 1024, 512, (int)Bb);
  softmax_bf<<<dim3(BN), blk, 0, stream>>>(U16(O_E1), inv_sqrt512);

  // o_h = attn_h @ V_h -> S0 (Q,K dead), bf16, columns [h*512,(h+1)*512)
  gemm(1, U16(O_E0), Nn * Nn, 1024, U16(O_S2) + 0LL * 512 * 1024, Nn * Nn, 1024,
       U16(O_S0) + 0,   Nn * Nn, 1024, nullptr, 0, 1024, 512, 1024, (int)Bb);
  gemm(1, U16(O_E1), Nn * Nn, 1024, U16(O_S2) + 1LL * 512 * 1024, Nn * Nn, 1024,
       U16(O_S0) + 512, Nn * Nn, 1024, nullptr, 0, 1024, 512, 1024, (int)Bb);

  // x = LN(o + aqq) -> bf16 -> S1 (K dead)
  ln1_k<<<dim3(BN), blk, 0, stream>>>(U16(O_S0), U16(O_E2), ln_g, ln_b, U16(O_S1));

  // h = relu(x @ ffn_w1) -> S2 (Vt dead)
  gemm(2, U16(O_S1), 0, 1024, U16(O_F1T), 0, 1024, U16(O_S2), 0, 1024, nullptr, 0, (int)BN, 1024, 1024, 1);

  // y0 = h @ ffn_w2 + x -> f32 into d_out
  gemm(3, U16(O_S2), 0, 1024, U16(O_F2T), 0, 1024, out, 0, 1024, U16(O_S1), 0, (int)BN, 1024, 1024, 1);

  // y = LN(y0) in place on d_out
  ln2_k<<<dim3(BN), blk, 0, stream>>>(out, fg, fb, out, 1e-6f);
}

// Round 3
// 999.876 us; speedup vs baseline: 1.0324x; 1.0324x over previous
//
#include <hip/hip_runtime.h>
#include <cstdint>

// ---------------- problem constants ----------------
static constexpr long long Bb = 16, Nn = 1024, FE = 512; // heads=2, g=512
static constexpr long long BN = Bb * Nn;        // 16384
static constexpr long long E1e = BN * FE;       // elems of [B,N,FE]
static constexpr long long E2n = BN * Nn;       // elems of [B,N,N]

// ---------------- workspace layout (bytes) ----------------
static constexpr long long O_WT  = 0;
static constexpr long long SZ_W512 = FE * FE * 2;          // 512x512 bf16
static constexpr long long O_WQT = O_WT + 6 * SZ_W512;
static constexpr long long SZ_W1K = Nn * Nn * 2;           // 1024x1024 bf16
static constexpr long long O_WKT = O_WQT + SZ_W1K;
static constexpr long long O_WVT = O_WKT + SZ_W1K;
static constexpr long long O_F1T = O_WVT + SZ_W1K;
static constexpr long long O_F2T = O_F1T + SZ_W1K;
static constexpr long long O_SLOTS = O_F2T + SZ_W1K;       // 13,631,488
static constexpr long long SLOT = E2n * 2;                 // 32 MiB
static constexpr long long O_S0 = O_SLOTS;                 // Cp -> Q -> o
static constexpr long long O_S1 = O_S0 + SLOT;             // Cq45 -> K -> x
static constexpr long long O_S2 = O_S1 + SLOT;             // Cq6 -> Vt -> h
static constexpr long long O_E0 = O_S2 + SLOT;             // ass -> scores h0
static constexpr long long O_E1 = O_E0 + SLOT;             // (FmsB|FsB) -> asq -> scores h1
static constexpr long long O_E2 = O_E1 + SLOT;             // (FqB|C2) -> aqq
static constexpr long long WS_NEED = O_E2 + SLOT;          // 214,958,080 (~205 MiB)
// temporaries parked inside E1/E2 before those are written:
static constexpr long long O_FMSB = O_E1;                  // dead after Cp
static constexpr long long O_FSB  = O_E1 + E1e * 2;        // dead after C2
static constexpr long long O_FQB  = O_E2;                  // dead after Cq45/Cq6
static constexpr long long O_C2   = O_E2 + E1e * 2;        // dead after asq

// ---------------- helpers ----------------
typedef __attribute__((ext_vector_type(8))) short short8;
typedef __attribute__((ext_vector_type(4))) float f32x4;

static __device__ __forceinline__ unsigned short f2bf(float f) {
  union { float f; unsigned u; } x; x.f = f;
  unsigned r = x.u + 0x7FFFu + ((x.u >> 16) & 1u);
  return (unsigned short)(r >> 16);
}
static __device__ __forceinline__ float bf2f(unsigned short h) {
  union { unsigned u; float f; } x; x.u = ((unsigned)h) << 16; return x.f;
}
static __device__ __forceinline__ void gload16(const void* g, void* l) {
  __builtin_amdgcn_global_load_lds(
      (const __attribute__((address_space(1))) unsigned int*)g,
      (__attribute__((address_space(3))) unsigned int*)l, 16, 0, 0);
}

// ---------------- bf16 NT GEMM: C[m,n] = sum_k A[m,k]*B[n,k] ----------------
// 128(M)x64(N) tile, BK=32, 4 waves each computing 64x32 (4x2 fragments).
// Batch z decodes as z1=z&15 (batch), z2=z>>4 (head): off = z1*s? + z2*h?.
// EP: 1 = bf16 out, 2 = bf16 relu out, 3 = f32 out + bf16 residual R.
template <int EP>
__global__ __launch_bounds__(256) void gemm_nt(
    const unsigned short* __restrict__ A, long long sA, long long hA, int lda,
    const unsigned short* __restrict__ B, long long sB, long long hB, int ldb,
    void* __restrict__ Cv, long long sC, long long hC, int ldc,
    const void* __restrict__ Rv, long long sR, int K) {
  __shared__ unsigned short lA[128 * 32];
  __shared__ unsigned short lB[64 * 32];
  const int tid = threadIdx.x;
  const int wave = tid >> 6, lane = tid & 63;
  const int wm = wave >> 1, wn = wave & 1;
  const int lrow = lane & 15, quad = lane >> 4;
  const int z = blockIdx.z, z1 = z & 15, z2 = z >> 4;
  const long long bm = (long long)blockIdx.x * 128;
  const long long bn = (long long)blockIdx.y * 64;
  const unsigned short* Ab = A + z1 * sA + z2 * hA + bm * lda;
  const unsigned short* Bbp = B + z1 * sB + z2 * hB + bn * ldb;
  const int srow = lane >> 2;        // row within 16-row staging group
  const int skol = (lane & 3) * 8;   // 8-elem k-offset
  const int g0 = wave * 2, g1 = wave * 2 + 1;

  f32x4 acc[4][2];
#pragma unroll
  for (int i = 0; i < 4; ++i)
#pragma unroll
    for (int j = 0; j < 2; ++j) acc[i][j] = (f32x4){0.f, 0.f, 0.f, 0.f};

  for (int k0 = 0; k0 < K; k0 += 32) {
    gload16(Ab + (long long)(g0 * 16 + srow) * lda + k0 + skol, &lA[g0 * 512 + lane * 8]);
    gload16(Ab + (long long)(g1 * 16 + srow) * lda + k0 + skol, &lA[g1 * 512 + lane * 8]);
    gload16(Bbp + (long long)(wave * 16 + srow) * ldb + k0 + skol, &lB[wave * 512 + lane * 8]);
    __syncthreads();
    short8 af[4], bfr[2];
#pragma unroll
    for (int t = 0; t < 4; ++t)
      af[t] = *(const short8*)&lA[(wm * 64 + t * 16 + lrow) * 32 + quad * 8];
#pragma unroll
    for (int u = 0; u < 2; ++u)
      bfr[u] = *(const short8*)&lB[(wn * 32 + u * 16 + lrow) * 32 + quad * 8];
#pragma unroll
    for (int mt = 0; mt < 4; ++mt)
#pragma unroll
      for (int nt = 0; nt < 2; ++nt)
        acc[mt][nt] = __builtin_amdgcn_mfma_f32_16x16x32_bf16(af[mt], bfr[nt], acc[mt][nt], 0, 0, 0);
    __syncthreads();
  }
  // epilogue: C/D map col=lane&15, row=quad*4+r (verified m89/m91)
  const long long cm = bm + wm * 64, cn = bn + wn * 32;
  const long long cz = z1 * sC + z2 * hC;
#pragma unroll
  for (int mt = 0; mt < 4; ++mt) {
#pragma unroll
    for (int nt = 0; nt < 2; ++nt) {
      long long col = cn + nt * 16 + lrow;
      long long row0 = cm + mt * 16 + quad * 4;
#pragma unroll
      for (int r = 0; r < 4; ++r) {
        long long row = row0 + r;
        float v = acc[mt][nt][r];
        long long idx = cz + row * ldc + col;
        if (EP == 1) ((unsigned short*)Cv)[idx] = f2bf(v);
        else if (EP == 2) ((unsigned short*)Cv)[idx] = f2bf(v > 0.f ? v : 0.f);
        else {
          float rr = bf2f(((const unsigned short*)Rv)[z1 * sR + row * ldc + col]);
          ((float*)Cv)[idx] = v + rr;
        }
      }
    }
  }
}

// ---------------- elementwise cast f32 -> bf16 ----------------
__global__ __launch_bounds__(256) void cast_bf16_k(const float* __restrict__ in,
                                                   unsigned short* __restrict__ out) {
  long long i = (long long)blockIdx.x * 256 + threadIdx.x;
  float4 v = ((const float4*)in)[i];
  ushort4 o; o.x = f2bf(v.x); o.y = f2bf(v.y); o.z = f2bf(v.z); o.w = f2bf(v.w);
  ((ushort4*)out)[i] = o;
}

// ---------------- transpose + cast f32 -> bf16: out[c][r] = in[r][c] ----------------
__global__ __launch_bounds__(256) void tcast_k(const float* __restrict__ in,
                                               unsigned short* __restrict__ out,
                                               int rows, int cols) {
  __shared__ float t[32][33];
  const int c0 = blockIdx.x * 32, r0 = blockIdx.y * 32;
  const int tx = threadIdx.x, ty = threadIdx.y; // block (32,8)
#pragma unroll
  for (int i = 0; i < 4; ++i) {
    int r = r0 + ty + i * 8;
    t[ty + i * 8][tx] = in[(long long)r * cols + c0 + tx];
  }
  __syncthreads();
#pragma unroll
  for (int i = 0; i < 4; ++i) {
    int c = c0 + ty + i * 8;
    out[(long long)c * rows + r0 + tx] = f2bf(t[tx][ty + i * 8]);
  }
}

// ---------------- in-place row softmax over bf16 (1024 cols), scaled ----------------
__global__ __launch_bounds__(256) void softmax_bf(unsigned short* __restrict__ S, float scale) {
  __shared__ float redA[4], redB[4];
  const long long row = blockIdx.x;
  const int t = threadIdx.x, wave = t >> 6, lane = t & 63;
  ushort4 u = ((ushort4*)(S + row * 1024))[t];
  float v0 = bf2f(u.x) * scale, v1 = bf2f(u.y) * scale, v2 = bf2f(u.z) * scale, v3 = bf2f(u.w) * scale;
  float m = fmaxf(fmaxf(v0, v1), fmaxf(v2, v3));
#pragma unroll
  for (int o = 32; o; o >>= 1) m = fmaxf(m, __shfl_down(m, o));
  if (lane == 0) redA[wave] = m;
  __syncthreads();
  m = fmaxf(fmaxf(redA[0], redA[1]), fmaxf(redA[2], redA[3]));
  float e0 = __expf(v0 - m), e1 = __expf(v1 - m), e2 = __expf(v2 - m), e3 = __expf(v3 - m);
  float s = e0 + e1 + e2 + e3;
#pragma unroll
  for (int o = 32; o; o >>= 1) s += __shfl_down(s, o);
  if (lane == 0) redB[wave] = s;
  __syncthreads();
  s = redB[0] + redB[1] + redB[2] + redB[3];
  float inv = 1.f / s;
  ushort4 ob; ob.x = f2bf(e0 * inv); ob.y = f2bf(e1 * inv); ob.z = f2bf(e2 * inv); ob.w = f2bf(e3 * inv);
  ((ushort4*)(S + row * 1024))[t] = ob;
}

// ---------------- LN1: x = LN(o + aqq)*g + b -> bf16 ----------------
__global__ __launch_bounds__(256) void ln1_k(const unsigned short* __restrict__ O,
                                             const unsigned short* __restrict__ Aq,
                                             const float* __restrict__ g, const float* __restrict__ b,
                                             unsigned short* __restrict__ xb) {
  __shared__ float redA[4], redB[4];
  const long long row = blockIdx.x;
  const int t = threadIdx.x, wave = t >> 6, lane = t & 63;
  ushort4 ou = ((const ushort4*)(O + row * 1024))[t];
  ushort4 au = ((const ushort4*)(Aq + row * 1024))[t];
  float v0 = bf2f(ou.x) + bf2f(au.x), v1 = bf2f(ou.y) + bf2f(au.y);
  float v2 = bf2f(ou.z) + bf2f(au.z), v3 = bf2f(ou.w) + bf2f(au.w);
  float s = v0 + v1 + v2 + v3;
  float q = v0 * v0 + v1 * v1 + v2 * v2 + v3 * v3;
#pragma unroll
  for (int o = 32; o; o >>= 1) { s += __shfl_down(s, o); q += __shfl_down(q, o); }
  if (lane == 0) { redA[wave] = s; redB[wave] = q; }
  __syncthreads();
  float S = redA[0] + redA[1] + redA[2] + redA[3];
  float Q = redB[0] + redB[1] + redB[2] + redB[3];
  float mu = S * (1.f / 1024.f);
  float var = Q * (1.f / 1024.f) - mu * mu;
  float rs = rsqrtf(var + 1e-5f);
  float4 gg = ((const float4*)g)[t], bbv = ((const float4*)b)[t];
  ushort4 ob;
  ob.x = f2bf((v0 - mu) * rs * gg.x + bbv.x);
  ob.y = f2bf((v1 - mu) * rs * gg.y + bbv.y);
  ob.z = f2bf((v2 - mu) * rs * gg.z + bbv.z);
  ob.w = f2bf((v3 - mu) * rs * gg.w + bbv.w);
  ((ushort4*)(xb + row * 1024))[t] = ob;
}

// ---------------- LN2: y = LN(y0)*g + b, f32 in-place safe ----------------
__global__ __launch_bounds__(256) void ln2_k(const float* __restrict__ Y,
                                             const float* __restrict__ g, const float* __restrict__ b,
                                             float* __restrict__ out, float eps) {
  __shared__ float redA[4], redB[4];
  const long long row = blockIdx.x;
  const int t = threadIdx.x, wave = t >> 6, lane = t & 63;
  float4 v = ((const float4*)(Y + row * 1024))[t];
  float s = v.x + v.y + v.z + v.w;
  float q = v.x * v.x + v.y * v.y + v.z * v.z + v.w * v.w;
#pragma unroll
  for (int o = 32; o; o >>= 1) { s += __shfl_down(s, o); q += __shfl_down(q, o); }
  if (lane == 0) { redA[wave] = s; redB[wave] = q; }
  __syncthreads();
  float S = redA[0] + redA[1] + redA[2] + redA[3];
  float Q = redB[0] + redB[1] + redB[2] + redB[3];
  float mu = S * (1.f / 1024.f);
  float var = Q * (1.f / 1024.f) - mu * mu;
  float rs = rsqrtf(var + eps);
  float4 gg = ((const float4*)g)[t], bbv = ((const float4*)b)[t];
  float4 o;
  o.x = (v.x - mu) * rs * gg.x + bbv.x;
  o.y = (v.y - mu) * rs * gg.y + bbv.y;
  o.z = (v.z - mu) * rs * gg.z + bbv.z;
  o.w = (v.w - mu) * rs * gg.w + bbv.w;
  ((float4*)(out + row * 1024))[t] = o;
}

// ---------------- launcher ----------------
extern "C" void kernel_launch(void* const* d_in, const int* in_sizes, int n_in,
                              void* d_out, int out_size, void* d_ws, size_t ws_size,
                              hipStream_t stream) {
  (void)in_sizes; (void)n_in; (void)out_size;
  if (ws_size < (size_t)WS_NEED) return; // diagnostic guard (absmax ~7.09 if hit)

  const float* Fs  = (const float*)d_in[0];
  const float* Fq  = (const float*)d_in[1];
  const float* Fms = (const float*)d_in[2];
  const float* Wm[6] = {(const float*)d_in[4], (const float*)d_in[5], (const float*)d_in[6],
                        (const float*)d_in[7], (const float*)d_in[8], (const float*)d_in[9]};
  const float* Wq = (const float*)d_in[10];
  const float* Wk = (const float*)d_in[11];
  const float* Wv = (const float*)d_in[12];
  const float* ln_g = (const float*)d_in[13];
  const float* ln_b = (const float*)d_in[14];
  const float* fw1 = (const float*)d_in[15];
  const float* fw2 = (const float*)d_in[16];
  const float* fg = (const float*)d_in[17];
  const float* fb = (const float*)d_in[18];
  float* out = (float*)d_out;
  uint8_t* ws = (uint8_t*)d_ws;
  auto U16 = [&](long long off) { return (unsigned short*)(ws + off); };

  const float inv_sqrt512 = 0.04419417382415922f; // 1/sqrt(512) == 1/sqrt(g)
  dim3 blk(256);

  auto gemm = [&](int ep, const unsigned short* A, long long sA, long long hA, int lda,
                  const unsigned short* B, long long sB, long long hB, int ldb,
                  void* C, long long sC, long long hC, int ldc, const void* R, long long sR,
                  int M, int N, int K, int batch) {
    dim3 g(M / 128, N / 64, batch);
    switch (ep) {
      case 1: gemm_nt<1><<<g, blk, 0, stream>>>(A, sA, hA, lda, B, sB, hB, ldb, C, sC, hC, ldc, R, sR, K); break;
      case 2: gemm_nt<2><<<g, blk, 0, stream>>>(A, sA, hA, lda, B, sB, hB, ldb, C, sC, hC, ldc, R, sR, K); break;
      default: gemm_nt<3><<<g, blk, 0, stream>>>(A, sA, hA, lda, B, sB, hB, ldb, C, sC, hC, ldc, R, sR, K); break;
    }
  };

  // ---- weights: transpose+cast to bf16 (W1T..W6T contiguous for N-merged projections) ----
  for (int i = 0; i < 6; ++i)
    tcast_k<<<dim3(16, 16), dim3(32, 8), 0, stream>>>(Wm[i], U16(O_WT + (long long)i * SZ_W512), 512, 512);
  tcast_k<<<dim3(32, 32), dim3(32, 8), 0, stream>>>(Wq,  U16(O_WQT), 1024, 1024);
  tcast_k<<<dim3(32, 32), dim3(32, 8), 0, stream>>>(Wk,  U16(O_WKT), 1024, 1024);
  tcast_k<<<dim3(32, 32), dim3(32, 8), 0, stream>>>(Wv,  U16(O_WVT), 1024, 1024);
  tcast_k<<<dim3(32, 32), dim3(32, 8), 0, stream>>>(fw1, U16(O_F1T), 1024, 1024);
  tcast_k<<<dim3(32, 32), dim3(32, 8), 0, stream>>>(fw2, U16(O_F2T), 1024, 1024);

  // ---- Phase A: affinities ----
  // Cp = Fms @ [W1|W2]  -> S0 [16384 x 1024]
  cast_bf16_k<<<dim3(E1e / 4 / 256), blk, 0, stream>>>(Fms, U16(O_FMSB));
  gemm(1, U16(O_FMSB), 0, 0, 512, U16(O_WT), 0, 0, 512, U16(O_S0), 0, 0, 1024,
       nullptr, 0, (int)BN, 1024, 512, 1);
  // ass = softmax(P0 P1^T / sqrt(512)) -> E0
  gemm(1, U16(O_S0), Nn * 1024, 0, 1024, U16(O_S0) + 512, Nn * 1024, 0, 1024,
       U16(O_E0), Nn * Nn, 0, 1024, nullptr, 0, 1024, 1024, 512, (int)Bb);
  softmax_bf<<<dim3(BN), blk, 0, stream>>>(U16(O_E0), inv_sqrt512);

  // casts for Fs, Fq; C2 = Fs@W3 ; Cq45 = Fq@[W4|W5] -> S1 ; Cq6 = Fq@W6 -> S2
  cast_bf16_k<<<dim3(E1e / 4 / 256), blk, 0, stream>>>(Fs, U16(O_FSB));
  cast_bf16_k<<<dim3(E1e / 4 / 256), blk, 0, stream>>>(Fq, U16(O_FQB));
  gemm(1, U16(O_FSB), 0, 0, 512, U16(O_WT + 2 * SZ_W512), 0, 0, 512, U16(O_C2), 0, 0, 512,
       nullptr, 0, (int)BN, 512, 512, 1);
  gemm(1, U16(O_FQB), 0, 0, 512, U16(O_WT + 3 * SZ_W512), 0, 0, 512, U16(O_S1), 0, 0, 1024,
       nullptr, 0, (int)BN, 1024, 512, 1);
  gemm(1, U16(O_FQB), 0, 0, 512, U16(O_WT + 5 * SZ_W512), 0, 0, 512, U16(O_S2), 0, 0, 512,
       nullptr, 0, (int)BN, 512, 512, 1);
  // asq = softmax(C2 Cq45[:, :512]^T) -> E1
  gemm(1, U16(O_C2), Nn * 512, 0, 512, U16(O_S1), Nn * 1024, 0, 1024,
       U16(O_E1), Nn * Nn, 0, 1024, nullptr, 0, 1024, 1024, 512, (int)Bb);
  softmax_bf<<<dim3(BN), blk, 0, stream>>>(U16(O_E1), inv_sqrt512);
  // aqq = softmax(Cq45[:, 512:] Cq6^T) -> E2
  gemm(1, U16(O_S1) + 512, Nn * 1024, 0, 1024, U16(O_S2), Nn * 512, 0, 512,
       U16(O_E2), Nn * Nn, 0, 1024, nullptr, 0, 1024, 1024, 512, (int)Bb);
  softmax_bf<<<dim3(BN), blk, 0, stream>>>(U16(O_E2), inv_sqrt512);

  const unsigned short* assB = U16(O_E0);
  const unsigned short* asqB = U16(O_E1);

  // ---- Phase B ----
  // Q = asq@Wq -> S0 ; K = ass@Wk -> S1 ; Vt[b][c][q] -> S2 (operand-swapped NT)
  gemm(1, asqB, 0, 0, 1024, U16(O_WQT), 0, 0, 1024, U16(O_S0), 0, 0, 1024, nullptr, 0, (int)BN, 1024, 1024, 1);
  gemm(1, assB, 0, 0, 1024, U16(O_WKT), 0, 0, 1024, U16(O_S1), 0, 0, 1024, nullptr, 0, (int)BN, 1024, 1024, 1);
  gemm(1, U16(O_WVT), 0, 0, 1024, asqB, Nn * Nn, 0, 1024, U16(O_S2), Nn * Nn, 0, 1024,
       nullptr, 0, 1024, 1024, 1024, (int)Bb);

  // attention scores, both heads in one batch-32 dispatch -> E0(:16), E1(z2=1)
  gemm(1, U16(O_S0), Nn * 1024, 512, 1024, U16(O_S1), Nn * 1024, 512, 1024,
       U16(O_E0), Nn * Nn, 16 * Nn * Nn, 1024, nullptr, 0, 1024, 1024, 512, 32);
  softmax_bf<<<dim3(2 * BN), blk, 0, stream>>>(U16(O_E0), inv_sqrt512);

  // o = attn @ V, both heads, batch 32 -> S0 (Q dead)
  gemm(1, U16(O_E0), Nn * Nn, 16 * Nn * Nn, 1024, U16(O_S2), Nn * Nn, 512 * 1024, 1024,
       U16(O_S0), Nn * 1024, 512, 1024, nullptr, 0, 1024, 512, 1024, 32);

  // x = LN(o + aqq) -> bf16 -> S1 (K dead)
  ln1_k<<<dim3(BN), blk, 0, stream>>>(U16(O_S0), U16(O_E2), ln_g, ln_b, U16(O_S1));

  // h = relu(x @ ffn_w1) -> S2 (Vt dead)
  gemm(2, U16(O_S1), 0, 0, 1024, U16(O_F1T), 0, 0, 1024, U16(O_S2), 0, 0, 1024,
       nullptr, 0, (int)BN, 1024, 1024, 1);

  // y0 = h @ ffn_w2 + x -> f32 into d_out
  gemm(3, U16(O_S2), 0, 0, 1024, U16(O_F2T), 0, 0, 1024, out, 0, 0, 1024,
       U16(O_S1), 0, (int)BN, 1024, 1024, 1);

  // y = LN(y0) in place on d_out
  ln2_k<<<dim3(BN), blk, 0, stream>>>(out, fg, fb, out, 1e-6f);
}

// Round 4
// 848.266 us; speedup vs baseline: 1.2169x; 1.1787x over previous
//
#include <hip/hip_runtime.h>
#include <cstdint>

// ---------------- problem constants ----------------
static constexpr long long Bb = 16, Nn = 1024, FE = 512; // heads=2, g=512
static constexpr long long BN = Bb * Nn;        // 16384
static constexpr long long E1e = BN * FE;       // elems of [B,N,FE]
static constexpr long long E2n = BN * Nn;       // elems of [B,N,N]

// ---------------- workspace layout (bytes) ----------------
static constexpr long long O_WT  = 0;
static constexpr long long SZ_W512 = FE * FE * 2;          // 512x512 bf16
static constexpr long long O_WQT = O_WT + 6 * SZ_W512;
static constexpr long long SZ_W1K = Nn * Nn * 2;           // 1024x1024 bf16
static constexpr long long O_WKT = O_WQT + SZ_W1K;
static constexpr long long O_WVT = O_WKT + SZ_W1K;
static constexpr long long O_F1T = O_WVT + SZ_W1K;
static constexpr long long O_F2T = O_F1T + SZ_W1K;
static constexpr long long O_SLOTS = O_F2T + SZ_W1K;       // 13,631,488
static constexpr long long SLOT = E2n * 2;                 // 32 MiB
static constexpr long long O_S0 = O_SLOTS;                 // Cp -> Q -> o
static constexpr long long O_S1 = O_S0 + SLOT;             // Cq45 -> K -> x
static constexpr long long O_S2 = O_S1 + SLOT;             // Cq6 -> Vt -> h
static constexpr long long O_E0 = O_S2 + SLOT;             // ass -> scores h0
static constexpr long long O_E1 = O_E0 + SLOT;             // (FmsB|FsB) -> asq -> scores h1
static constexpr long long O_E2 = O_E1 + SLOT;             // (FqB|C2) -> aqq
static constexpr long long WS_NEED = O_E2 + SLOT;          // 214,958,080 (~205 MiB)
// temporaries parked inside E1/E2 before those are written:
static constexpr long long O_FMSB = O_E1;                  // dead after Cp
static constexpr long long O_FSB  = O_E1 + E1e * 2;        // dead after C2 (asq overwrites)
static constexpr long long O_FQB  = O_E2;                  // dead after Cq45/Cq6
static constexpr long long O_C2   = O_E2 + E1e * 2;        // dead after asq (aqq overwrites)

// ---------------- helpers ----------------
typedef __attribute__((ext_vector_type(8))) short short8;
typedef __attribute__((ext_vector_type(4))) float f32x4;

static __device__ __forceinline__ unsigned short f2bf(float f) {
  union { float f; unsigned u; } x; x.f = f;
  unsigned r = x.u + 0x7FFFu + ((x.u >> 16) & 1u);
  return (unsigned short)(r >> 16);
}
static __device__ __forceinline__ float bf2f(unsigned short h) {
  union { unsigned u; float f; } x; x.u = ((unsigned)h) << 16; return x.f;
}
static __device__ __forceinline__ void gload16(const void* g, void* l) {
  __builtin_amdgcn_global_load_lds(
      (const __attribute__((address_space(1))) unsigned int*)g,
      (__attribute__((address_space(3))) unsigned int*)l, 16, 0, 0);
}

// ---------------- bf16 NT GEMM: C[m,n] = sum_k A[m,k]*B[n,k] ----------------
// 128(M)x64(N) tile, BK=64 (two 32-k panels per barrier-pair), 16x16x32 MFMA.
// L2 swizzle: chunks of 8 M-blocks sweep all N-blocks.
// Batch z decodes z1=z&15, z2=z>>4: operand offset = z1*s? + z2*h?.
// EP: 1 = bf16 out, 2 = bf16 relu out, 3 = f32 out + bf16 residual R.
template <int EP>
__global__ __launch_bounds__(256) void gemm_nt(
    const unsigned short* __restrict__ A, long long sA, long long hA, int lda,
    const unsigned short* __restrict__ B, long long sB, long long hB, int ldb,
    void* __restrict__ Cv, long long sC, long long hC, int ldc,
    const void* __restrict__ Rv, long long sR, int K) {
  __shared__ unsigned short lA[128 * 64];  // two 128x32 panels
  __shared__ unsigned short lB[64 * 64];   // two 64x32 panels
  const int tid = threadIdx.x;
  const int wave = tid >> 6, lane = tid & 63;
  const int wm = wave >> 1, wn = wave & 1;
  const int lrow = lane & 15, quad = lane >> 4;
  const int z = blockIdx.z, z1 = z & 15, z2 = z >> 4;
  // swizzle (gridDim.x always a multiple of 8)
  const int gy = gridDim.y;
  const int bid = blockIdx.x + gridDim.x * blockIdx.y;
  const int chunk = 8 * gy;
  const int bx = (bid / chunk) * 8 + (bid % 8);
  const int by = (bid % chunk) / 8;
  const long long bm = (long long)bx * 128;
  const long long bn = (long long)by * 64;
  const unsigned short* Ab = A + z1 * sA + z2 * hA + bm * lda;
  const unsigned short* Bbp = B + z1 * sB + z2 * hB + bn * ldb;
  const int srow = lane >> 2;        // row within 16-row staging group
  const int skol = (lane & 3) * 8;   // 8-elem k-offset
  const int g0 = wave * 2, g1 = wave * 2 + 1;

  f32x4 acc[4][2];
#pragma unroll
  for (int i = 0; i < 4; ++i)
#pragma unroll
    for (int j = 0; j < 2; ++j) acc[i][j] = (f32x4){0.f, 0.f, 0.f, 0.f};

  for (int k0 = 0; k0 < K; k0 += 64) {
    const unsigned short* Ak = Ab + k0 + skol;
    const unsigned short* Bk = Bbp + k0 + skol;
    gload16(Ak + (long long)(g0 * 16 + srow) * lda,      &lA[g0 * 512 + lane * 8]);
    gload16(Ak + (long long)(g1 * 16 + srow) * lda,      &lA[g1 * 512 + lane * 8]);
    gload16(Ak + (long long)(g0 * 16 + srow) * lda + 32, &lA[4096 + g0 * 512 + lane * 8]);
    gload16(Ak + (long long)(g1 * 16 + srow) * lda + 32, &lA[4096 + g1 * 512 + lane * 8]);
    gload16(Bk + (long long)(wave * 16 + srow) * ldb,      &lB[wave * 512 + lane * 8]);
    gload16(Bk + (long long)(wave * 16 + srow) * ldb + 32, &lB[2048 + wave * 512 + lane * 8]);
    __syncthreads();
#pragma unroll
    for (int p = 0; p < 2; ++p) {
      short8 af[4], bfr[2];
#pragma unroll
      for (int t = 0; t < 4; ++t)
        af[t] = *(const short8*)&lA[p * 4096 + (wm * 64 + t * 16 + lrow) * 32 + quad * 8];
#pragma unroll
      for (int u = 0; u < 2; ++u)
        bfr[u] = *(const short8*)&lB[p * 2048 + (wn * 32 + u * 16 + lrow) * 32 + quad * 8];
#pragma unroll
      for (int mt = 0; mt < 4; ++mt)
#pragma unroll
        for (int nt = 0; nt < 2; ++nt)
          acc[mt][nt] = __builtin_amdgcn_mfma_f32_16x16x32_bf16(af[mt], bfr[nt], acc[mt][nt], 0, 0, 0);
    }
    __syncthreads();
  }
  // epilogue: C/D map col=lane&15, row=quad*4+r (verified m89/m91)
  const long long cm = bm + wm * 64, cn = bn + wn * 32;
  const long long cz = z1 * sC + z2 * hC;
#pragma unroll
  for (int mt = 0; mt < 4; ++mt) {
#pragma unroll
    for (int nt = 0; nt < 2; ++nt) {
      long long col = cn + nt * 16 + lrow;
      long long row0 = cm + mt * 16 + quad * 4;
#pragma unroll
      for (int r = 0; r < 4; ++r) {
        long long row = row0 + r;
        float v = acc[mt][nt][r];
        long long idx = cz + row * ldc + col;
        if (EP == 1) ((unsigned short*)Cv)[idx] = f2bf(v);
        else if (EP == 2) ((unsigned short*)Cv)[idx] = f2bf(v > 0.f ? v : 0.f);
        else {
          float rr = bf2f(((const unsigned short*)Rv)[z1 * sR + row * ldc + col]);
          ((float*)Cv)[idx] = v + rr;
        }
      }
    }
  }
}

// ---------------- merged cast f32 -> bf16 for Fs, Fq, Fms ----------------
__global__ __launch_bounds__(256) void cast3_k(const float* __restrict__ i0,
                                               const float* __restrict__ i1,
                                               const float* __restrict__ i2,
                                               unsigned short* o0, unsigned short* o1,
                                               unsigned short* o2) {
  const float* in = (blockIdx.y == 0) ? i0 : (blockIdx.y == 1) ? i1 : i2;
  unsigned short* out = (blockIdx.y == 0) ? o0 : (blockIdx.y == 1) ? o1 : o2;
  long long i = (long long)blockIdx.x * 256 + threadIdx.x;
  float4 v = ((const float4*)in)[i];
  ushort4 o; o.x = f2bf(v.x); o.y = f2bf(v.y); o.z = f2bf(v.z); o.w = f2bf(v.w);
  ((ushort4*)out)[i] = o;
}

// ---------------- merged transpose+cast: z selects source ----------------
// out[z] is outb + z*(rows*cols); out[c][r] = in[r][c]
__global__ __launch_bounds__(256) void tcast6_k(const float* p0, const float* p1,
                                                const float* p2, const float* p3,
                                                const float* p4, const float* p5,
                                                unsigned short* outb, int rows, int cols) {
  const float* src[6] = {p0, p1, p2, p3, p4, p5};
  const float* in = src[blockIdx.z];
  unsigned short* out = outb + (long long)blockIdx.z * rows * cols;
  __shared__ float t[32][33];
  const int c0 = blockIdx.x * 32, r0 = blockIdx.y * 32;
  const int tx = threadIdx.x, ty = threadIdx.y; // block (32,8)
#pragma unroll
  for (int i = 0; i < 4; ++i) {
    int r = r0 + ty + i * 8;
    t[ty + i * 8][tx] = in[(long long)r * cols + c0 + tx];
  }
  __syncthreads();
#pragma unroll
  for (int i = 0; i < 4; ++i) {
    int c = c0 + ty + i * 8;
    out[(long long)c * rows + r0 + tx] = f2bf(t[tx][ty + i * 8]);
  }
}

// ---------------- in-place row softmax over bf16 (1024 cols), scaled ----------------
__global__ __launch_bounds__(256) void softmax_bf(unsigned short* __restrict__ S, float scale) {
  __shared__ float redA[4], redB[4];
  const long long row = blockIdx.x;
  const int t = threadIdx.x, wave = t >> 6, lane = t & 63;
  ushort4 u = ((ushort4*)(S + row * 1024))[t];
  float v0 = bf2f(u.x) * scale, v1 = bf2f(u.y) * scale, v2 = bf2f(u.z) * scale, v3 = bf2f(u.w) * scale;
  float m = fmaxf(fmaxf(v0, v1), fmaxf(v2, v3));
#pragma unroll
  for (int o = 32; o; o >>= 1) m = fmaxf(m, __shfl_down(m, o));
  if (lane == 0) redA[wave] = m;
  __syncthreads();
  m = fmaxf(fmaxf(redA[0], redA[1]), fmaxf(redA[2], redA[3]));
  float e0 = __expf(v0 - m), e1 = __expf(v1 - m), e2 = __expf(v2 - m), e3 = __expf(v3 - m);
  float s = e0 + e1 + e2 + e3;
#pragma unroll
  for (int o = 32; o; o >>= 1) s += __shfl_down(s, o);
  if (lane == 0) redB[wave] = s;
  __syncthreads();
  s = redB[0] + redB[1] + redB[2] + redB[3];
  float inv = 1.f / s;
  ushort4 ob; ob.x = f2bf(e0 * inv); ob.y = f2bf(e1 * inv); ob.z = f2bf(e2 * inv); ob.w = f2bf(e3 * inv);
  ((ushort4*)(S + row * 1024))[t] = ob;
}

// ---------------- LN1: x = LN(o + aqq)*g + b -> bf16 ----------------
__global__ __launch_bounds__(256) void ln1_k(const unsigned short* __restrict__ O,
                                             const unsigned short* __restrict__ Aq,
                                             const float* __restrict__ g, const float* __restrict__ b,
                                             unsigned short* __restrict__ xb) {
  __shared__ float redA[4], redB[4];
  const long long row = blockIdx.x;
  const int t = threadIdx.x, wave = t >> 6, lane = t & 63;
  ushort4 ou = ((const ushort4*)(O + row * 1024))[t];
  ushort4 au = ((const ushort4*)(Aq + row * 1024))[t];
  float v0 = bf2f(ou.x) + bf2f(au.x), v1 = bf2f(ou.y) + bf2f(au.y);
  float v2 = bf2f(ou.z) + bf2f(au.z), v3 = bf2f(ou.w) + bf2f(au.w);
  float s = v0 + v1 + v2 + v3;
  float q = v0 * v0 + v1 * v1 + v2 * v2 + v3 * v3;
#pragma unroll
  for (int o = 32; o; o >>= 1) { s += __shfl_down(s, o); q += __shfl_down(q, o); }
  if (lane == 0) { redA[wave] = s; redB[wave] = q; }
  __syncthreads();
  float S = redA[0] + redA[1] + redA[2] + redA[3];
  float Q = redB[0] + redB[1] + redB[2] + redB[3];
  float mu = S * (1.f / 1024.f);
  float var = Q * (1.f / 1024.f) - mu * mu;
  float rs = rsqrtf(var + 1e-5f);
  float4 gg = ((const float4*)g)[t], bbv = ((const float4*)b)[t];
  ushort4 ob;
  ob.x = f2bf((v0 - mu) * rs * gg.x + bbv.x);
  ob.y = f2bf((v1 - mu) * rs * gg.y + bbv.y);
  ob.z = f2bf((v2 - mu) * rs * gg.z + bbv.z);
  ob.w = f2bf((v3 - mu) * rs * gg.w + bbv.w);
  ((ushort4*)(xb + row * 1024))[t] = ob;
}

// ---------------- LN2: y = LN(y0)*g + b, f32 in-place safe ----------------
__global__ __launch_bounds__(256) void ln2_k(const float* __restrict__ Y,
                                             const float* __restrict__ g, const float* __restrict__ b,
                                             float* __restrict__ out, float eps) {
  __shared__ float redA[4], redB[4];
  const long long row = blockIdx.x;
  const int t = threadIdx.x, wave = t >> 6, lane = t & 63;
  float4 v = ((const float4*)(Y + row * 1024))[t];
  float s = v.x + v.y + v.z + v.w;
  float q = v.x * v.x + v.y * v.y + v.z * v.z + v.w * v.w;
#pragma unroll
  for (int o = 32; o; o >>= 1) { s += __shfl_down(s, o); q += __shfl_down(q, o); }
  if (lane == 0) { redA[wave] = s; redB[wave] = q; }
  __syncthreads();
  float S = redA[0] + redA[1] + redA[2] + redA[3];
  float Q = redB[0] + redB[1] + redB[2] + redB[3];
  float mu = S * (1.f / 1024.f);
  float var = Q * (1.f / 1024.f) - mu * mu;
  float rs = rsqrtf(var + eps);
  float4 gg = ((const float4*)g)[t], bbv = ((const float4*)b)[t];
  float4 o;
  o.x = (v.x - mu) * rs * gg.x + bbv.x;
  o.y = (v.y - mu) * rs * gg.y + bbv.y;
  o.z = (v.z - mu) * rs * gg.z + bbv.z;
  o.w = (v.w - mu) * rs * gg.w + bbv.w;
  ((float4*)(out + row * 1024))[t] = o;
}

// ---------------- launcher ----------------
extern "C" void kernel_launch(void* const* d_in, const int* in_sizes, int n_in,
                              void* d_out, int out_size, void* d_ws, size_t ws_size,
                              hipStream_t stream) {
  (void)in_sizes; (void)n_in; (void)out_size;
  if (ws_size < (size_t)WS_NEED) return; // diagnostic guard (absmax ~7.09 if hit)

  const float* Fs  = (const float*)d_in[0];
  const float* Fq  = (const float*)d_in[1];
  const float* Fms = (const float*)d_in[2];
  const float* Wm[6] = {(const float*)d_in[4], (const float*)d_in[5], (const float*)d_in[6],
                        (const float*)d_in[7], (const float*)d_in[8], (const float*)d_in[9]};
  const float* Wq = (const float*)d_in[10];
  const float* Wk = (const float*)d_in[11];
  const float* Wv = (const float*)d_in[12];
  const float* ln_g = (const float*)d_in[13];
  const float* ln_b = (const float*)d_in[14];
  const float* fw1 = (const float*)d_in[15];
  const float* fw2 = (const float*)d_in[16];
  const float* fg = (const float*)d_in[17];
  const float* fb = (const float*)d_in[18];
  float* out = (float*)d_out;
  uint8_t* ws = (uint8_t*)d_ws;
  auto U16 = [&](long long off) { return (unsigned short*)(ws + off); };

  const float inv_sqrt512 = 0.04419417382415922f; // 1/sqrt(512) == 1/sqrt(g)
  dim3 blk(256);

  auto gemm = [&](int ep, const unsigned short* A, long long sA, long long hA, int lda,
                  const unsigned short* B, long long sB, long long hB, int ldb,
                  void* C, long long sC, long long hC, int ldc, const void* R, long long sR,
                  int M, int N, int K, int batch) {
    dim3 g(M / 128, N / 64, batch);
    switch (ep) {
      case 1: gemm_nt<1><<<g, blk, 0, stream>>>(A, sA, hA, lda, B, sB, hB, ldb, C, sC, hC, ldc, R, sR, K); break;
      case 2: gemm_nt<2><<<g, blk, 0, stream>>>(A, sA, hA, lda, B, sB, hB, ldb, C, sC, hC, ldc, R, sR, K); break;
      default: gemm_nt<3><<<g, blk, 0, stream>>>(A, sA, hA, lda, B, sB, hB, ldb, C, sC, hC, ldc, R, sR, K); break;
    }
  };

  // ---- weights: transpose+cast to bf16 (merged dispatches) ----
  tcast6_k<<<dim3(16, 16, 6), dim3(32, 8), 0, stream>>>(
      Wm[0], Wm[1], Wm[2], Wm[3], Wm[4], Wm[5], U16(O_WT), 512, 512);
  tcast6_k<<<dim3(32, 32, 5), dim3(32, 8), 0, stream>>>(
      Wq, Wk, Wv, fw1, fw2, fw2 /*unused*/, U16(O_WQT), 1024, 1024);
  // ---- input casts (before any affinity output is written) ----
  cast3_k<<<dim3(E1e / 4 / 256, 3), blk, 0, stream>>>(
      Fs, Fq, Fms, U16(O_FSB), U16(O_FQB), U16(O_FMSB));

  // ---- Phase A: affinities ----
  // Cp = Fms @ [W1|W2]  -> S0 [16384 x 1024]
  gemm(1, U16(O_FMSB), 0, 0, 512, U16(O_WT), 0, 0, 512, U16(O_S0), 0, 0, 1024,
       nullptr, 0, (int)BN, 1024, 512, 1);
  // ass = softmax(P0 P1^T / sqrt(512)) -> E0
  gemm(1, U16(O_S0), Nn * 1024, 0, 1024, U16(O_S0) + 512, Nn * 1024, 0, 1024,
       U16(O_E0), Nn * Nn, 0, 1024, nullptr, 0, 1024, 1024, 512, (int)Bb);
  softmax_bf<<<dim3(BN), blk, 0, stream>>>(U16(O_E0), inv_sqrt512);

  // C2 = Fs@W3 ; Cq45 = Fq@[W4|W5] -> S1 ; Cq6 = Fq@W6 -> S2
  gemm(1, U16(O_FSB), 0, 0, 512, U16(O_WT + 2 * SZ_W512), 0, 0, 512, U16(O_C2), 0, 0, 512,
       nullptr, 0, (int)BN, 512, 512, 1);
  gemm(1, U16(O_FQB), 0, 0, 512, U16(O_WT + 3 * SZ_W512), 0, 0, 512, U16(O_S1), 0, 0, 1024,
       nullptr, 0, (int)BN, 1024, 512, 1);
  gemm(1, U16(O_FQB), 0, 0, 512, U16(O_WT + 5 * SZ_W512), 0, 0, 512, U16(O_S2), 0, 0, 512,
       nullptr, 0, (int)BN, 512, 512, 1);
  // asq = softmax(C2 Cq45[:, :512]^T) -> E1
  gemm(1, U16(O_C2), Nn * 512, 0, 512, U16(O_S1), Nn * 1024, 0, 1024,
       U16(O_E1), Nn * Nn, 0, 1024, nullptr, 0, 1024, 1024, 512, (int)Bb);
  softmax_bf<<<dim3(BN), blk, 0, stream>>>(U16(O_E1), inv_sqrt512);
  // aqq = softmax(Cq45[:, 512:] Cq6^T) -> E2
  gemm(1, U16(O_S1) + 512, Nn * 1024, 0, 1024, U16(O_S2), Nn * 512, 0, 512,
       U16(O_E2), Nn * Nn, 0, 1024, nullptr, 0, 1024, 1024, 512, (int)Bb);
  softmax_bf<<<dim3(BN), blk, 0, stream>>>(U16(O_E2), inv_sqrt512);

  const unsigned short* assB = U16(O_E0);
  const unsigned short* asqB = U16(O_E1);

  // ---- Phase B ----
  // merged K+Q: z2=0 -> K = ass@Wk -> S1 ; z2=1 -> Q = asq@Wq -> S0
  gemm(1, assB, Nn * Nn, E2n, 1024,
       U16(O_WKT), 0, -(long long)(SZ_W1K / 2), 1024,
       U16(O_S1), Nn * 1024, -(long long)E2n, 1024,
       nullptr, 0, 1024, 1024, 1024, 32);
  // Vt[b][c][q] -> S2 (operand-swapped NT)
  gemm(1, U16(O_WVT), 0, 0, 1024, asqB, Nn * Nn, 0, 1024, U16(O_S2), Nn * Nn, 0, 1024,
       nullptr, 0, 1024, 1024, 1024, (int)Bb);

  // attention scores, both heads in one batch-32 dispatch -> E0(z2=0), E1(z2=1)
  gemm(1, U16(O_S0), Nn * 1024, 512, 1024, U16(O_S1), Nn * 1024, 512, 1024,
       U16(O_E0), Nn * Nn, 16 * Nn * Nn, 1024, nullptr, 0, 1024, 1024, 512, 32);
  softmax_bf<<<dim3(2 * BN), blk, 0, stream>>>(U16(O_E0), inv_sqrt512);

  // o = attn @ V, both heads, batch 32 -> S0 (Q dead)
  gemm(1, U16(O_E0), Nn * Nn, 16 * Nn * Nn, 1024, U16(O_S2), Nn * Nn, 512 * 1024, 1024,
       U16(O_S0), Nn * 1024, 512, 1024, nullptr, 0, 1024, 512, 1024, 32);

  // x = LN(o + aqq) -> bf16 -> S1 (K dead)
  ln1_k<<<dim3(BN), blk, 0, stream>>>(U16(O_S0), U16(O_E2), ln_g, ln_b, U16(O_S1));

  // h = relu(x @ ffn_w1) -> S2 (Vt dead)
  gemm(2, U16(O_S1), 0, 0, 1024, U16(O_F1T), 0, 0, 1024, U16(O_S2), 0, 0, 1024,
       nullptr, 0, (int)BN, 1024, 1024, 1);

  // y0 = h @ ffn_w2 + x -> f32 into d_out
  gemm(3, U16(O_S2), 0, 0, 1024, U16(O_F2T), 0, 0, 1024, out, 0, 0, 1024,
       U16(O_S1), 0, (int)BN, 1024, 1024, 1);

  // y = LN(y0) in place on d_out
  ln2_k<<<dim3(BN), blk, 0, stream>>>(out, fg, fb, out, 1e-6f);
}